// Round 6
// baseline (468.771 us; speedup 1.0000x reference)
//
#include <hip/hip_runtime.h>
#include <math.h>

#define BN 8
#define C1 256
#define C2 128
#define WD 512

typedef float  f32x4  __attribute__((ext_vector_type(4)));
typedef short  bf16x8 __attribute__((ext_vector_type(8)));
typedef unsigned short ushort_t;
typedef ushort_t us8 __attribute__((ext_vector_type(8)));
typedef ushort_t us4 __attribute__((ext_vector_type(4)));

__device__ __forceinline__ int clampi(int v, int lo, int hi) {
    return v < lo ? lo : (v > hi ? hi : v);
}
__device__ __forceinline__ float bf2f(ushort_t u) {
    return __uint_as_float(((unsigned int)u) << 16);
}
__device__ __forceinline__ ushort_t f2bf(float f) {
    unsigned int u = __float_as_uint(f);
    u = (u + 0x7fff + ((u >> 16) & 1)) >> 16;   // RNE
    return (ushort_t)u;
}

// ---------------- affine (wave-per-output): s1, s2, n1, n2 ----------------
__global__ __launch_bounds__(256)
void affine_kernel(const float* __restrict__ w, const float* __restrict__ n,
                   const float* __restrict__ A1w, const float* __restrict__ A1b,
                   const float* __restrict__ B1w, const float* __restrict__ B1b,
                   const float* __restrict__ A2w, const float* __restrict__ A2b,
                   const float* __restrict__ B2w, const float* __restrict__ B2b,
                   float* __restrict__ s1, float* __restrict__ s2,
                   float* __restrict__ n1, float* __restrict__ n2) {
    int tid = threadIdx.x;
    int gw = blockIdx.x * 4 + (tid >> 6);
    int lane = tid & 63;
    if (gw >= BN * 896) return;
    int b = gw / 896;
    int j = gw % 896;
    const float* vec; const float* M; const float* bias; float* out; int o;
    if (j < 256)      { o = j;       vec = w + b * WD; M = A1w; bias = A1b; out = s1 + b * 256; }
    else if (j < 512) { o = j - 256; vec = w + b * WD; M = A2w; bias = A2b; out = s2 + b * 256; }
    else if (j < 768) { o = j - 512; vec = n + b * WD; M = B1w; bias = B1b; out = n1 + b * 256; }
    else              { o = j - 768; vec = n + b * WD; M = B2w; bias = B2b; out = n2 + b * 128; }
    const float* row = M + (size_t)o * WD;
    int k0 = lane * 8;
    float4 v0 = *(const float4*)(vec + k0), v1 = *(const float4*)(vec + k0 + 4);
    float4 r0 = *(const float4*)(row + k0), r1 = *(const float4*)(row + k0 + 4);
    float acc = v0.x*r0.x + v0.y*r0.y + v0.z*r0.z + v0.w*r0.w
              + v1.x*r1.x + v1.y*r1.y + v1.z*r1.z + v1.w*r1.w;
    #pragma unroll
    for (int m = 1; m < 64; m <<= 1) acc += __shfl_xor(acc, m, 64);
    if (lane == 0) out[o] = acc + bias[o];
}

// ---------------- demod (wave-per-output) ----------------
__global__ __launch_bounds__(256)
void demod_kernel(const float* __restrict__ cw1, const float* __restrict__ cw2,
                  const float* __restrict__ s1, const float* __restrict__ s2,
                  float* __restrict__ d1, float* __restrict__ d2) {
    int tid = threadIdx.x;
    int gw = blockIdx.x * 4 + (tid >> 6);
    int lane = tid & 63;
    if (gw >= BN * 384) return;
    int b = gw / 384;
    int j = gw % 384;
    const float* wbase; const float* s; float* dout; int o;
    if (j < 256) { o = j;       wbase = cw1; s = s1 + b * 256; dout = d1 + b * 256; }
    else         { o = j - 256; wbase = cw2; s = s2 + b * 256; dout = d2 + b * 128; }
    float acc = 0.f;
    #pragma unroll
    for (int i = 0; i < 4; i++) {
        int ic = lane * 4 + i;
        float sv = s[ic]; sv *= sv;
        const float* wk = wbase + ((size_t)o * 256 + ic) * 9;
        float t = 0.f;
        #pragma unroll
        for (int k = 0; k < 9; k++) t += wk[k] * wk[k];
        acc += t * sv;
    }
    #pragma unroll
    for (int m = 1; m < 64; m <<= 1) acc += __shfl_xor(acc, m, 64);
    if (lane == 0) dout[o] = rsqrtf(acc + 1e-5f);
}

// ------- weight repack -> bf16 fragment-contiguous layout -------
// wTf[((tap*OC16 + ocRow)*8 + kc)*512 + (col*4+quad)*8 + j]
//   holds w[oc=ocRow*16+col][ic=kc*32+quad*8+j][tap]
// so each wave's A-frag load (col=lane&15, quad=lane>>4) is 1024 B contiguous.
__global__ __launch_bounds__(256)
void wprep_kernel(const float* __restrict__ cw1, const float* __restrict__ cw2,
                  ushort_t* __restrict__ wTf1, ushort_t* __restrict__ wTf2) {
    int idx = blockIdx.x * 256 + threadIdx.x;
    if (idx < 589824) {
        int j = idx & 7, quad = (idx >> 3) & 3, col = (idx >> 5) & 15;
        int kc = (idx >> 9) & 7, ocRow = (idx >> 12) & 15, tap = idx >> 16;
        int oc = ocRow * 16 + col, ic = kc * 32 + quad * 8 + j;
        wTf1[idx] = f2bf(cw1[((size_t)oc * 256 + ic) * 9 + tap]);
    } else if (idx < 589824 + 294912) {
        int e = idx - 589824;
        int j = e & 7, quad = (e >> 3) & 3, col = (e >> 5) & 15;
        int kc = (e >> 9) & 7, ocRow = (e >> 12) & 7, tap = e >> 15;
        int oc = ocRow * 16 + col, ic = kc * 32 + quad * 8 + j;
        wTf2[e] = f2bf(cw2[((size_t)oc * 256 + ic) * 9 + tap]);
    }
}

// -------- xprep: x NCHW f32 -> xTp[b][66][66][256] bf16, styles folded, self-zeroed border --------
__global__ __launch_bounds__(256)
void xprep_kernel(const float* __restrict__ x, const float* __restrict__ s1,
                  ushort_t* __restrict__ xTp) {
    int b = blockIdx.y;
    int flat = blockIdx.x * 256 + threadIdx.x;
    if (flat >= 66 * 66 * 32) return;
    int ic8 = flat & 31, pxl = flat >> 5;
    int gy = pxl / 66, gx = pxl - gy * 66;
    us8 h = {0, 0, 0, 0, 0, 0, 0, 0};
    if (gy >= 1 && gy <= 64 && gx >= 1 && gx <= 64) {
        const float* xb = x + (((size_t)b * C1) << 12) + ((gy - 1) << 6) + (gx - 1);
        float4 slo = *(const float4*)(s1 + b * 256 + ic8 * 8);
        float4 shi = *(const float4*)(s1 + b * 256 + ic8 * 8 + 4);
        float sv[8] = {slo.x, slo.y, slo.z, slo.w, shi.x, shi.y, shi.z, shi.w};
        #pragma unroll
        for (int j = 0; j < 8; j++) {
            float v = xb[((size_t)(ic8 * 8 + j)) << 12];
            h[j] = f2bf(v * sv[j]);
        }
    }
    *(us8*)(xTp + (size_t)b * 66 * 66 * 256 + (size_t)pxl * 256 + ic8 * 8) = h;
}

// -------- upsample: y1T -> y1up[b][130][130][256], *s2 folded, self-zeroed border --------
__global__ __launch_bounds__(256)
void upsample_kernel(const ushort_t* __restrict__ y1T, const float* __restrict__ s2,
                     ushort_t* __restrict__ y1up) {
    int b = blockIdx.y;
    int flat = blockIdx.x * 256 + threadIdx.x;
    if (flat >= 130 * 130 * 32) return;
    int ic8 = flat & 31, pxl = flat >> 5;
    int uy0 = pxl / 130, ux0 = pxl - uy0 * 130;
    us8 h = {0, 0, 0, 0, 0, 0, 0, 0};
    if (uy0 >= 1 && uy0 <= 128 && ux0 >= 1 && ux0 <= 128) {
        int uy = uy0 - 1, ux = ux0 - 1;
        int jyA; float wyA;
        if (uy & 1) { jyA = uy >> 1;       wyA = 0.75f; }
        else        { jyA = (uy >> 1) - 1; wyA = 0.25f; }
        int jxA; float wxA;
        if (ux & 1) { jxA = ux >> 1;       wxA = 0.75f; }
        else        { jxA = (ux >> 1) - 1; wxA = 0.25f; }
        int yA = clampi(jyA, 0, 63), yB = clampi(jyA + 1, 0, 63);
        int xA = clampi(jxA, 0, 63), xB = clampi(jxA + 1, 0, 63);
        float wyB = 1.f - wyA, wxB = 1.f - wxA;
        const ushort_t* yb = y1T + (size_t)b * 64 * 64 * 256 + ic8 * 8;
        us8 qAA = *(const us8*)(yb + (size_t)(yA * 64 + xA) * 256);
        us8 qAB = *(const us8*)(yb + (size_t)(yA * 64 + xB) * 256);
        us8 qBA = *(const us8*)(yb + (size_t)(yB * 64 + xA) * 256);
        us8 qBB = *(const us8*)(yb + (size_t)(yB * 64 + xB) * 256);
        float4 slo = *(const float4*)(s2 + b * 256 + ic8 * 8);
        float4 shi = *(const float4*)(s2 + b * 256 + ic8 * 8 + 4);
        float sv[8] = {slo.x, slo.y, slo.z, slo.w, shi.x, shi.y, shi.z, shi.w};
        #pragma unroll
        for (int j = 0; j < 8; j++) {
            float v = wyA * (wxA * bf2f(qAA[j]) + wxB * bf2f(qAB[j]))
                    + wyB * (wxA * bf2f(qBA[j]) + wxB * bf2f(qBB[j]));
            h[j] = f2bf(v * sv[j]);
        }
    }
    *(us8*)(y1up + (size_t)b * 130 * 130 * 256 + (size_t)pxl * 256 + ic8 * 8) = h;
}

// =========== conv MFMA: 64 oc x (16x16 px) per block ===========
// A-frags (weights) come straight from global (L2-resident, cross-wave dedup via L1);
// activations double-buffered in LDS -> ONE barrier per kc. 41.5 KB LDS -> 3 blocks/CU.
template<int ROWSTR, int OC16, int TPR, bool IS_CONV2>
__global__ __launch_bounds__(256, 3)
void conv_mfma(const ushort_t* __restrict__ inp, const ushort_t* __restrict__ wTf,
               const float* __restrict__ dmod, const float* __restrict__ nza,
               ushort_t* __restrict__ outT,
               const float* __restrict__ rgb_in, const float* __restrict__ rw,
               const float* __restrict__ rb, float* __restrict__ xout,
               float* __restrict__ rgbo) {
    __shared__ __align__(16) ushort_t actS[2][18 * 18 * 32];   // 2 x 20736 B
    int b = blockIdx.z, ocg = blockIdx.y, tile = blockIdx.x;
    int ty0 = (tile / TPR) * 16, tx0 = (tile % TPR) * 16;
    int tid = threadIdx.x, lane = tid & 63, wave = tid >> 6;
    int col = lane & 15, quad = lane >> 4;

    const ushort_t* inb = inp + (size_t)b * ROWSTR * ROWSTR * 256;

    int actOff[6]; bool actOk[6];
    #pragma unroll
    for (int i = 0; i < 6; i++) {
        int u = tid + 256 * i;
        actOk[i] = (u < 1296);
        int pxl = u >> 2, ic8 = u & 3;
        int py = pxl / 18, px = pxl - py * 18;
        actOff[i] = ((ty0 + py) * ROWSTR + tx0 + px) * 256 + ic8 * 8;
    }
    // A-frag base: wTf[((tap*OC16 + ocg*4+mt)*8 + kc)*512 + (col*4+quad)*8]
    const ushort_t* wbase = wTf + (size_t)(ocg * 4) * 4096 + (col * 4 + quad) * 8;

    us8 aReg[6];
#define LOADK(KC) { \
    _Pragma("unroll") for (int i = 0; i < 6; i++) \
        if (actOk[i]) aReg[i] = *(const us8*)(inb + actOff[i] + (KC) * 32); }
#define STOREK(BUFI) { \
    _Pragma("unroll") for (int i = 0; i < 6; i++) \
        if (actOk[i]) *(us8*)(actS[BUFI] + (size_t)(tid + 256 * i) * 8) = aReg[i]; }

    f32x4 acc[4][4];
    #pragma unroll
    for (int mt = 0; mt < 4; mt++)
        #pragma unroll
        for (int nt = 0; nt < 4; nt++) acc[mt][nt] = (f32x4)(0.f);

    LOADK(0);
    STOREK(0);
    __syncthreads();

    for (int kc = 0; kc < 8; kc++) {
        int cur = kc & 1;
        if (kc < 7) LOADK(kc + 1);
        const ushort_t* lb = actS[cur];
        #pragma unroll
        for (int tap = 0; tap < 9; tap++) {
            const int dy = tap / 3, dx = tap % 3;
            bf16x8 a[4], bb[4];
            #pragma unroll
            for (int mt = 0; mt < 4; mt++)
                a[mt] = *(const bf16x8*)(wbase + (size_t)tap * OC16 * 4096 + mt * 4096 + kc * 512);
            #pragma unroll
            for (int nt = 0; nt < 4; nt++)
                bb[nt] = *(const bf16x8*)(lb + (((4 * wave + nt + dy) * 18 + col + dx) * 32 + quad * 8));
            #pragma unroll
            for (int mt = 0; mt < 4; mt++)
                #pragma unroll
                for (int nt = 0; nt < 4; nt++)
                    acc[mt][nt] = __builtin_amdgcn_mfma_f32_16x16x32_bf16(a[mt], bb[nt], acc[mt][nt], 0, 0, 0);
        }
        if (kc < 7) STOREK(cur ^ 1);
        __syncthreads();
    }
#undef LOADK
#undef STOREK

    if (!IS_CONV2) {
        #pragma unroll
        for (int mt = 0; mt < 4; mt++) {
            int oc0 = ocg * 64 + mt * 16 + quad * 4;
            float4 dv = *(const float4*)(dmod + b * 256 + oc0);
            float4 nv = *(const float4*)(nza + b * 256 + oc0);
            float dva[4] = {dv.x, dv.y, dv.z, dv.w};
            float nva[4] = {nv.x, nv.y, nv.z, nv.w};
            #pragma unroll
            for (int nt = 0; nt < 4; nt++) {
                int gy = ty0 + 4 * wave + nt, gx = tx0 + col;
                us4 h;
                #pragma unroll
                for (int r = 0; r < 4; r++) {
                    float t = acc[mt][nt][r] * dva[r] + nva[r];
                    t = (t >= 0.f) ? t : 0.1f * t;
                    h[r] = f2bf(t);
                }
                *(us4*)(outT + (size_t)b * 64 * 64 * 256 + (size_t)(gy * 64 + gx) * 256 + oc0) = h;
            }
        }
    } else {
        float dva[4][4], nva[4][4], rwa[3][4][4];
        #pragma unroll
        for (int mt = 0; mt < 4; mt++) {
            int oc0 = ocg * 64 + mt * 16 + quad * 4;
            float4 dv = *(const float4*)(dmod + b * 128 + oc0);
            float4 nv = *(const float4*)(nza + b * 128 + oc0);
            dva[mt][0] = dv.x; dva[mt][1] = dv.y; dva[mt][2] = dv.z; dva[mt][3] = dv.w;
            nva[mt][0] = nv.x; nva[mt][1] = nv.y; nva[mt][2] = nv.z; nva[mt][3] = nv.w;
            #pragma unroll
            for (int c = 0; c < 3; c++) {
                float4 rv = *(const float4*)(rw + c * 128 + oc0);
                rwa[c][mt][0] = rv.x; rwa[c][mt][1] = rv.y; rwa[c][mt][2] = rv.z; rwa[c][mt][3] = rv.w;
            }
        }
        #pragma unroll
        for (int nt = 0; nt < 4; nt++) {
            int uy = ty0 + 4 * wave + nt, ux = tx0 + col;
            float pc0 = 0.f, pc1 = 0.f, pc2 = 0.f;
            #pragma unroll
            for (int mt = 0; mt < 4; mt++) {
                int oc0 = ocg * 64 + mt * 16 + quad * 4;
                #pragma unroll
                for (int r = 0; r < 4; r++) {
                    float t = acc[mt][nt][r] * dva[mt][r] + nva[mt][r];
                    t = (t >= 0.f) ? t : 0.1f * t;
                    xout[(((size_t)b * 128 + oc0 + r) << 14) + (uy << 7) + ux] = t;
                    pc0 += rwa[0][mt][r] * t;
                    pc1 += rwa[1][mt][r] * t;
                    pc2 += rwa[2][mt][r] * t;
                }
            }
            // residual+bias added exactly once per pixel (quad 0 of ocg 0)
            if (ocg == 0 && quad == 0) {
                int jyA; float wyA;
                if (uy & 1) { jyA = uy >> 1;       wyA = 0.75f; }
                else        { jyA = (uy >> 1) - 1; wyA = 0.25f; }
                int jxA; float wxA;
                if (ux & 1) { jxA = ux >> 1;       wxA = 0.75f; }
                else        { jxA = (ux >> 1) - 1; wxA = 0.25f; }
                int yA = clampi(jyA, 0, 63), yB = clampi(jyA + 1, 0, 63);
                int xA = clampi(jxA, 0, 63), xB = clampi(jxA + 1, 0, 63);
                float wyB = 1.f - wyA, wxB = 1.f - wxA;
                const float* rp3 = rgb_in + (((size_t)b * 3) << 12);
                float up[3];
                #pragma unroll
                for (int c = 0; c < 3; c++) {
                    const float* rc = rp3 + ((size_t)c << 12);
                    up[c] = wyA * (wxA * rc[(yA << 6) + xA] + wxB * rc[(yA << 6) + xB])
                          + wyB * (wxA * rc[(yB << 6) + xA] + wxB * rc[(yB << 6) + xB]);
                }
                pc0 += rb[0] + up[0];
                pc1 += rb[1] + up[1];
                pc2 += rb[2] + up[2];
            }
            const float S = 0.70710678118654752f;
            atomicAdd(rgbo + (((size_t)b * 3 + 0) << 14) + (uy << 7) + ux, pc0 * S);
            atomicAdd(rgbo + (((size_t)b * 3 + 1) << 14) + (uy << 7) + ux, pc1 * S);
            atomicAdd(rgbo + (((size_t)b * 3 + 2) << 14) + (uy << 7) + ux, pc2 * S);
        }
    }
}

extern "C" void kernel_launch(void* const* d_in, const int* in_sizes, int n_in,
                              void* d_out, int out_size, void* d_ws, size_t ws_size,
                              hipStream_t stream) {
    (void)in_sizes; (void)n_in; (void)out_size; (void)ws_size;
    const float* x     = (const float*)d_in[0];
    const float* w     = (const float*)d_in[1];
    const float* n     = (const float*)d_in[2];
    const float* rgb   = (const float*)d_in[3];
    const float* cw1   = (const float*)d_in[4];
    const float* A1w   = (const float*)d_in[5];
    const float* A1b   = (const float*)d_in[6];
    const float* B1w   = (const float*)d_in[7];
    const float* B1b   = (const float*)d_in[8];
    const float* cw2   = (const float*)d_in[9];
    const float* A2w   = (const float*)d_in[10];
    const float* A2b   = (const float*)d_in[11];
    const float* B2w   = (const float*)d_in[12];
    const float* B2b   = (const float*)d_in[13];
    const float* rgbw  = (const float*)d_in[14];
    const float* rgbb  = (const float*)d_in[15];

    char* ws = (char*)d_ws;
    float* s1 = (float*)(ws);
    float* s2 = (float*)(ws + 8192);
    float* d1 = (float*)(ws + 16384);
    float* d2 = (float*)(ws + 24576);
    float* n1 = (float*)(ws + 28672);
    float* n2 = (float*)(ws + 36864);
    ushort_t* wTf1 = (ushort_t*)(ws + 40960);          // 1179648 B
    ushort_t* wTf2 = (ushort_t*)(ws + 1220608);        // 589824 B
    ushort_t* xTp  = (ushort_t*)(ws + 1810432);        // 17842176 B
    ushort_t* y1up = (ushort_t*)(ws + 19652608);       // 69222400 B
    ushort_t* y1T  = (ushort_t*)(ws + 88875008);       // 16777216 B

    float* xout = (float*)d_out;
    float* rgbo = xout + (size_t)BN * C2 * 128 * 128;

    // rgb output is atomically accumulated -> zero it; padded buffers self-zero their borders
    hipMemsetAsync(rgbo, 0, (size_t)BN * 3 * 128 * 128 * 4, stream);

    affine_kernel<<<1792, 256, 0, stream>>>(w, n, A1w, A1b, B1w, B1b, A2w, A2b, B2w, B2b,
                                            s1, s2, n1, n2);
    demod_kernel<<<768, 256, 0, stream>>>(cw1, cw2, s1, s2, d1, d2);
    wprep_kernel<<<3456, 256, 0, stream>>>(cw1, cw2, wTf1, wTf2);
    xprep_kernel<<<dim3((66 * 66 * 32 + 255) / 256, BN), 256, 0, stream>>>(x, s1, xTp);
    conv_mfma<66, 16, 4, false><<<dim3(16, 4, BN), 256, 0, stream>>>(
        xTp, wTf1, d1, n1, y1T, nullptr, nullptr, nullptr, nullptr, nullptr);
    upsample_kernel<<<dim3((130 * 130 * 32 + 255) / 256, BN), 256, 0, stream>>>(y1T, s2, y1up);
    conv_mfma<130, 8, 8, true><<<dim3(64, 2, BN), 256, 0, stream>>>(
        y1up, wTf2, d2, n2, nullptr, rgb, rgbw, rgbb, xout, rgbo);
}